// Round 12
// baseline (439.728 us; speedup 1.0000x reference)
//
#include <hip/hip_runtime.h>

#define DIN   256
#define HID   8192
#define BATCH 8192
#define TOPK  32
#define BM    32
#define HHALF 4096
#define NCH   16          // hid chunks per half (256 latents each)
#define NS1   48          // per-half approx top-k kept
#define MRG   96          // merged candidates per row
#define NS2   48          // exact-rerank count
#define AS_LD 264         // 528 B row stride
#define XF_LD 260
#define TW    24          // tournament pops per wave per row
#define MG    (8*TW)      // 192 merged per row per half
#define MG_LD 193
#define LLEN  8           // per-(thread,row) register list depth
#define GK_OFF ((size_t)4 << 20)   // key buffer offset in ws (after 4MiB wsb)

typedef __bf16 bf16x8 __attribute__((ext_vector_type(8)));
typedef unsigned short u16x8 __attribute__((ext_vector_type(8)));
typedef float f32x4v __attribute__((ext_vector_type(4)));

__device__ unsigned g_qcnt[2];   // per-half work-queue tickets (reset each launch)

__device__ __forceinline__ unsigned short f2bf(float f) {
  unsigned x = __builtin_bit_cast(unsigned, f);
  x = x + 0x7fffu + ((x >> 16) & 1u);   // RNE, finite only
  return (unsigned short)(x >> 16);
}

// ---------------- Kernel A: W_enc f32 -> bf16, MFMA-B-fragment layout ----
__global__ __launch_bounds__(512) void wenc_cast(
    const float* __restrict__ Wenc, unsigned short* __restrict__ wsb)
{
  if (blockIdx.x == 0 && threadIdx.x < 2) g_qcnt[threadIdx.x] = 0u;
  const int g = (int)blockIdx.x * 512 + (int)threadIdx.x;  // 262144 units
  const int h = g >> 5, u = g & 31, kg = u >> 2, quad = u & 3;
  const float* src = Wenc + (size_t)h * DIN + kg * 32 + quad * 8;
  float4 a = *(const float4*)src;
  float4 b = *(const float4*)(src + 4);
  u16x8 o;
  o[0] = f2bf(a.x); o[1] = f2bf(a.y); o[2] = f2bf(a.z); o[3] = f2bf(a.w);
  o[4] = f2bf(b.x); o[5] = f2bf(b.y); o[6] = f2bf(b.z); o[7] = f2bf(b.w);
  *(u16x8*)(wsb + ((size_t)(((h >> 4) * 8 + kg) * 64 + quad * 16 + (h & 15))) * 8) = o;
}

union U1 { unsigned short As[BM][AS_LD]; unsigned mg[BM][MG_LD]; };  // 24.7 KB

// ---------------- Kernel B1: encoder GEMM + per-half approx top-48 ----
// r11: blockIdx%8 XCD guess FAILED (wsb read rate == 5 TB/s LLC, not 34 TB/s
// L2). Now each block reads its real XCD via s_getreg(HW_REG_XCC_ID)
// [HW-verified, m09] and self-selects the W_enc half = XCD parity through
// device-scope atomic queues (steal path keeps exact coverage for any
// dispatch shape) -> all co-XCD blocks stream the SAME 2MB half -> true
// L2 residency.
__global__ __launch_bounds__(512) __attribute__((amdgpu_waves_per_eu(2, 2)))
void sae_enc(
    const float* __restrict__ x,    const float* __restrict__ benc,
    const float* __restrict__ bdec, const unsigned short* __restrict__ wsb,
    unsigned* __restrict__ gkeys)
{
  __shared__ __align__(16) U1 u1;
  __shared__ int sh_assign;

  const int tid  = (int)threadIdx.x;
  const int wave = tid >> 6;
  const int lane = tid & 63;
  const int quad = lane >> 4;
  const int ln15 = lane & 15;

  if (tid == 0) {
    unsigned xcc;
    asm volatile("s_getreg_b32 %0, hwreg(HW_REG_XCC_ID)" : "=s"(xcc));
    const int pref = (int)(xcc & 1u);
    int hs, rt;
    unsigned slot = atomicAdd(&g_qcnt[pref], 1u);
    if (slot < 256u) { hs = pref; rt = (int)slot; }
    else             { hs = 1 - pref; rt = (int)atomicAdd(&g_qcnt[1 - pref], 1u); }
    sh_assign = (rt << 1) | hs;
  }
  __syncthreads();
  const int hs = sh_assign & 1;
  const int mb = (sh_assign >> 1) * BM;

  // ---- stage bf16(x - b_dec) rows into LDS ----
  {
    const int r = tid >> 4, seg = tid & 15;
    const float* xs = x + (size_t)(mb + r) * DIN + seg * 16;
    const float* bs = bdec + seg * 16;
    #pragma unroll
    for (int j = 0; j < 4; ++j) {
      float4 xv = *(const float4*)(xs + 4 * j);
      float4 bv = *(const float4*)(bs + 4 * j);
      unsigned short* dst = &u1.As[r][seg * 16 + 4 * j];
      dst[0] = f2bf(xv.x - bv.x); dst[1] = f2bf(xv.y - bv.y);
      dst[2] = f2bf(xv.z - bv.z); dst[3] = f2bf(xv.w - bv.w);
    }
  }
  __syncthreads();

  // A-fragments (verified 16x16x32 layout): A[m=lane&15][k=quad*8+j]
  bf16x8 afrag[2][8];
  #pragma unroll
  for (int mt = 0; mt < 2; ++mt)
    #pragma unroll
    for (int gk = 0; gk < 8; ++gk)
      afrag[mt][gk] = *(const bf16x8*)&u1.As[mt * 16 + ln15][gk * 32 + quad * 8];
  __syncthreads();   // afrag reads done before mg overlays As

  // key = (bf16(v)<<16) | (8191-h): u32 order == (value desc, idx asc); unique.
  unsigned lst[8][LLEN];
  #pragma unroll
  for (int s = 0; s < 8; ++s)
    #pragma unroll
    for (int j = 0; j < LLEN; ++j) lst[s][j] = 0u;

  f32x4v acc[2][2];
  #pragma unroll
  for (int mt = 0; mt < 2; ++mt)
    #pragma unroll
    for (int nt = 0; nt < 2; ++nt)
      #pragma unroll
      for (int i = 0; i < 4; ++i) acc[mt][nt][i] = 0.0f;

  for (int c = 0; c < NCH; ++c) {
    #pragma unroll
    for (int nt = 0; nt < 2; ++nt) {
      const int tile = hs * 256 + c * 16 + wave * 2 + nt;
      const unsigned short* bp = wsb + ((size_t)tile * 512 + lane) * 8;
      bf16x8 bfrag[8];
      #pragma unroll
      for (int kg = 0; kg < 8; ++kg)
        bfrag[kg] = *(const bf16x8*)(bp + (size_t)kg * 512);
      #pragma unroll
      for (int kg = 0; kg < 8; ++kg) {
        acc[0][nt] = __builtin_amdgcn_mfma_f32_16x16x32_bf16(afrag[0][kg], bfrag[kg], acc[0][nt], 0, 0, 0);
        acc[1][nt] = __builtin_amdgcn_mfma_f32_16x16x32_bf16(afrag[1][kg], bfrag[kg], acc[1][nt], 0, 0, 0);
      }
    }
    // epilogue: +b_enc, relu, register sorted-list insert
    #pragma unroll
    for (int mt = 0; mt < 2; ++mt) {
      #pragma unroll
      for (int nt = 0; nt < 2; ++nt) {
        const int h  = hs * HHALF + c * 256 + wave * 32 + nt * 16 + ln15;
        const float be = benc[h];
        const unsigned idxpart = (unsigned)(8191 - h);
        #pragma unroll
        for (int i = 0; i < 4; ++i) {
          const int s = mt * 4 + i;
          float v = acc[mt][nt][i] + be;
          acc[mt][nt][i] = 0.0f;
          v = v > 0.0f ? v : 0.0f;
          unsigned k = ((unsigned)f2bf(v) << 16) | idxpart;
          if (k > lst[s][LLEN - 1]) {
            #pragma unroll
            for (int j = 0; j < LLEN; ++j) {
              unsigned cur = lst[s][j];
              bool put = k > cur;
              lst[s][j] = put ? k : cur;
              k = put ? cur : k;
            }
          }
        }
      }
    }
  }

  // per-wave 16-lane tournament -> top-TW per row per wave
  #pragma unroll
  for (int s = 0; s < 8; ++s) {
    const int row = (s >> 2) * 16 + quad * 4 + (s & 3);
    unsigned head = lst[s][0];
    for (int t = 0; t < TW; ++t) {
      unsigned m = head;
      #pragma unroll
      for (int d = 1; d < 16; d <<= 1) {
        unsigned o = __shfl_xor(m, d, 16);
        m = o > m ? o : m;
      }
      if (head == m) {
        u1.mg[row][wave * TW + t] = m;
        #pragma unroll
        for (int j = 0; j < LLEN - 1; ++j) lst[s][j] = lst[s][j + 1];
        lst[s][LLEN - 1] = 0u;
      }
      head = lst[s][0];
    }
  }
  __syncthreads();

  // rank-select top-NS1 of 192 (keys unique) -> global key buffer
  {
    const int row = tid >> 4, l16 = tid & 15;
    unsigned myk[12];
    int rank[12];
    #pragma unroll
    for (int j = 0; j < 12; ++j) {
      myk[j]  = u1.mg[row][l16 + 16 * j];
      rank[j] = 0;
    }
    for (int e = 0; e < MG; ++e) {
      unsigned k2 = u1.mg[row][e];
      #pragma unroll
      for (int j = 0; j < 12; ++j) rank[j] += (k2 > myk[j]) ? 1 : 0;
    }
    #pragma unroll
    for (int j = 0; j < 12; ++j)
      if (rank[j] < NS1)
        gkeys[(size_t)(mb + row) * MRG + hs * NS1 + rank[j]] = myk[j];
  }
}

// ---------------- Kernel B2: merge halves + exact f64 rerank + decode ----
__global__ __launch_bounds__(512) void sae_dec(
    const float* __restrict__ x,    const float* __restrict__ Wenc,
    const float* __restrict__ benc, const float* __restrict__ Wdec,
    const float* __restrict__ bdec, const unsigned* __restrict__ gkeys,
    float* __restrict__ out)
{
  __shared__ unsigned mk[BM][MRG];
  __shared__ __align__(16) float xf[BM][XF_LD];
  __shared__ float tv[BM][NS2];
  __shared__ int   ti[BM][NS2];

  const int tid = (int)threadIdx.x;
  const int mb  = (int)blockIdx.x * BM;

  for (int i = tid; i < BM * MRG; i += 512)
    mk[i / MRG][i % MRG] = gkeys[(size_t)mb * MRG + i];

  {  // stage exact f32 sae_in rows
    const int r = tid >> 4, seg = tid & 15;
    const float* xs = x + (size_t)(mb + r) * DIN + seg * 16;
    const float* bs = bdec + seg * 16;
    #pragma unroll
    for (int j = 0; j < 4; ++j) {
      float4 xv = *(const float4*)(xs + 4 * j);
      float4 bv = *(const float4*)(bs + 4 * j);
      float4 d;
      d.x = xv.x - bv.x; d.y = xv.y - bv.y; d.z = xv.z - bv.z; d.w = xv.w - bv.w;
      *(float4*)&xf[r][seg * 16 + 4 * j] = d;
    }
  }
  __syncthreads();

  // merge: rank-select top-NS2 of 96 (keys unique)
  {
    const int row = tid >> 4, l16 = tid & 15;
    unsigned myk[6];
    int rk[6];
    #pragma unroll
    for (int j = 0; j < 6; ++j) {
      myk[j] = mk[row][l16 + 16 * j];
      rk[j]  = 0;
    }
    for (int e = 0; e < MRG; ++e) {
      unsigned k2 = mk[row][e];
      #pragma unroll
      for (int j = 0; j < 6; ++j) rk[j] += (k2 > myk[j]) ? 1 : 0;
    }
    #pragma unroll
    for (int j = 0; j < 6; ++j)
      if (rk[j] < NS2) ti[row][rk[j]] = 8191 - (int)(myk[j] & 0xFFFFu);
  }
  __syncthreads();

  // exact f64 rerank of NS2 candidates/row; 4 threads per (row,cand) pair
  {
    const int sub = tid & 3, pidx = tid >> 2;   // 128 pair-slots per pass
    for (int j = 0; j < (BM * NS2) / 128; ++j) {
      int pp = j * 128 + pidx;
      int row = pp / NS2, cand = pp - row * NS2;
      int h = ti[row][cand];
      const float* wp = Wenc + (size_t)h * DIN + sub * 64;
      const float* xp = &xf[row][sub * 64];
      double accd = 0.0;
      #pragma unroll
      for (int kk = 0; kk < 16; ++kk) {
        float4 w  = *(const float4*)(wp + 4 * kk);
        float4 xv = *(const float4*)(xp + 4 * kk);
        accd += (double)xv.x * (double)w.x;
        accd += (double)xv.y * (double)w.y;
        accd += (double)xv.z * (double)w.z;
        accd += (double)xv.w * (double)w.w;
      }
      accd += __shfl_down(accd, 2, 4);
      accd += __shfl_down(accd, 1, 4);
      if (sub == 0) {
        float ev = (float)accd + benc[h];
        ev = ev > 0.0f ? ev : 0.0f;   // relu before ranking (matches ref)
        tv[row][cand] = ev;
      }
    }
  }
  __syncthreads();
  if (tid < BM) {  // exact top-32 of NS2 (value desc, idx asc)
    float* tvr = tv[tid];
    int*   tir = ti[tid];
    for (int s = 0; s < TOPK; ++s) {
      float bv = tvr[s]; int bi = tir[s]; int bp = s;
      for (int t2 = s + 1; t2 < NS2; ++t2) {
        float v2 = tvr[t2]; int i2 = tir[t2];
        if (v2 > bv || (v2 == bv && (unsigned)i2 < (unsigned)bi)) {
          bv = v2; bi = i2; bp = t2;
        }
      }
      if (bp != s) {
        tvr[bp] = tvr[s]; tir[bp] = tir[s];
        tvr[s] = bv; tir[s] = bi;
      }
    }
  }
  __syncthreads();

  // decode: out[b,:] = sum z_k * W_dec[idx_k,:] + b_dec  (all f32)
  {
    const int r = tid >> 4, seg = tid & 15, d0 = seg * 16;
    float od[16];
    #pragma unroll
    for (int j = 0; j < 4; ++j) {
      float4 b = *(const float4*)(bdec + d0 + 4 * j);
      od[4 * j] = b.x; od[4 * j + 1] = b.y; od[4 * j + 2] = b.z; od[4 * j + 3] = b.w;
    }
    for (int s = 0; s < TOPK; ++s) {
      float v = tv[r][s];
      if (!(v > 0.0f)) break;    // sorted desc
      int h = ti[r][s];
      const float* wp = Wdec + (size_t)h * DIN + d0;
      #pragma unroll
      for (int j = 0; j < 4; ++j) {
        float4 w = *(const float4*)(wp + 4 * j);
        od[4 * j]     += v * w.x;
        od[4 * j + 1] += v * w.y;
        od[4 * j + 2] += v * w.z;
        od[4 * j + 3] += v * w.w;
      }
    }
    float* op = out + (size_t)(mb + r) * DIN + d0;
    #pragma unroll
    for (int j = 0; j < 4; ++j) {
      float4 o;
      o.x = od[4 * j]; o.y = od[4 * j + 1]; o.z = od[4 * j + 2]; o.w = od[4 * j + 3];
      *(float4*)(op + 4 * j) = o;
    }
  }
}

extern "C" void kernel_launch(void* const* d_in, const int* in_sizes, int n_in,
                              void* d_out, int out_size, void* d_ws, size_t ws_size,
                              hipStream_t stream) {
  const float* x    = (const float*)d_in[0];
  const float* Wenc = (const float*)d_in[1];
  const float* benc = (const float*)d_in[2];
  const float* Wdec = (const float*)d_in[3];
  const float* bdec = (const float*)d_in[4];
  float* out = (float*)d_out;
  unsigned short* wsb = (unsigned short*)d_ws;                 // 4 MiB bf16 fragments
  unsigned* gkeys = (unsigned*)((char*)d_ws + GK_OFF);         // 3 MiB keys

  wenc_cast<<<dim3((HID * DIN / 8) / 512), dim3(512), 0, stream>>>(Wenc, wsb);
  sae_enc<<<dim3(2 * BATCH / BM), dim3(512), 0, stream>>>(x, benc, bdec, wsb, gkeys);
  sae_dec<<<dim3(BATCH / BM), dim3(512), 0, stream>>>(x, Wenc, benc, Wdec, bdec, gkeys, out);
}